// Round 2
// baseline (7873.093 us; speedup 1.0000x reference)
//
#include <hip/hip_runtime.h>

typedef short bf8 __attribute__((ext_vector_type(8)));
typedef float f32x4 __attribute__((ext_vector_type(4)));

static constexpr int BB = 256;   // batch
static constexpr int TT = 128;   // time
static constexpr int II = 512;   // input features
static constexpr int HH = 1024;  // hidden
static constexpr int OO = 512;   // fc out features
static constexpr int G4 = 4096;  // 4*H

static constexpr size_t OUT_H = (size_t)BB * OO;          // h (f32) starts here in d_out
static constexpr size_t OUT_C = OUT_H + (size_t)BB * HH;  // c (f32) starts here
static constexpr size_t HBUF  = (size_t)BB * HH;          // ping-pong h buffer stride (elems)

__device__ __forceinline__ float bf2f(ushort u) {
    unsigned v = ((unsigned)u) << 16;
    return __builtin_bit_cast(float, v);
}
__device__ __forceinline__ ushort f2bf(float f) {
    unsigned x = __builtin_bit_cast(unsigned, f);
    x = x + 0x7FFFu + ((x >> 16) & 1u);   // round-to-nearest-even
    return (ushort)(x >> 16);
}
__device__ __forceinline__ float sigf(float x) { return 1.0f / (1.0f + __expf(-x)); }
__device__ __forceinline__ float tanhf_(float x) { return 2.0f * sigf(2.0f * x) - 1.0f; }

// ---- manual grid barrier (all 256 blocks resident: 144KB LDS => 1 block/CU) ----
__device__ __forceinline__ void gridbar(int* bar) {
    __threadfence();
    __syncthreads();
    if (threadIdx.x == 0) {
        int g = __hip_atomic_load(bar + 1, __ATOMIC_RELAXED, __HIP_MEMORY_SCOPE_AGENT);
        int a = __hip_atomic_fetch_add(bar + 0, 1, __ATOMIC_ACQ_REL, __HIP_MEMORY_SCOPE_AGENT);
        if (a == 255) {
            __hip_atomic_store(bar + 0, 0, __ATOMIC_RELAXED, __HIP_MEMORY_SCOPE_AGENT);
            __hip_atomic_store(bar + 1, g + 1, __ATOMIC_RELEASE, __HIP_MEMORY_SCOPE_AGENT);
        } else {
            while (__hip_atomic_load(bar + 1, __ATOMIC_ACQUIRE, __HIP_MEMORY_SCOPE_AGENT) == g)
                __builtin_amdgcn_s_sleep(2);
        }
        __threadfence();
    }
    __syncthreads();
}

__global__ void k_init(int* bar) {
    if (threadIdx.x < 8) bar[threadIdx.x] = 0;
}

// ---- f32 -> bf16 flat cast (W_fc) ----
__global__ void k_cast(const float* __restrict__ src, ushort* __restrict__ dst, int n4) {
    int i = blockIdx.x * blockDim.x + threadIdx.x;
    int stride = gridDim.x * blockDim.x;
    for (; i < n4; i += stride) {
        float4 v = ((const float4*)src)[i];
        ushort4 o;
        o.x = f2bf(v.x); o.y = f2bf(v.y); o.z = f2bf(v.z); o.w = f2bf(v.w);
        ((ushort4*)dst)[i] = o;
    }
}

// ---- permute gate rows + cast W, fold biases ----
// permuted index p = j*64 + gate*16 + hc  ->  original row = gate*1024 + j*16 + hc
__global__ void k_prep_w(const float* __restrict__ w, ushort* __restrict__ wp,
                         const float* __restrict__ bi, const float* __restrict__ bh,
                         float* __restrict__ bp, int Kdim) {
    int p = blockIdx.x;
    int orig = ((p >> 4) & 3) * HH + ((p >> 6) << 4) + (p & 15);
    const float* src = w + (size_t)orig * Kdim;
    ushort* dst = wp + (size_t)p * Kdim;
    for (int k = threadIdx.x; k < Kdim; k += 256) dst[k] = f2bf(src[k]);
    if (threadIdx.x == 0 && bp) bp[p] = bi[orig] + bh[orig];
}

// ---- persistent kernel: per segment { pre-chunk GEMM ; SEG recurrent steps } ----
// 256 blocks x 256 threads. block = (rb: 64 batch rows) x (j: 64 permuted gate cols).
// W_hh slice resident in LDS (128 KiB); pregemm staging 16 KiB; total 144 KiB.
__global__ __launch_bounds__(256) void k_main(
    const float* __restrict__ x, const ushort* __restrict__ wpih,
    const float* __restrict__ bp, ushort* __restrict__ pre,
    const ushort* __restrict__ wphh, ushort* __restrict__ hbf,
    float* __restrict__ dout, int* bar, int SEG) {
    __shared__ ushort wl[32 * 2048];  // [ko][c 0..63][kk 0..31] = 128 KiB
    __shared__ ushort Al[128 * 32];   // 8 KiB pregemm A stage
    __shared__ ushort Bl[128 * 32];   // 8 KiB pregemm B stage

    int tid = threadIdx.x;
    int bid = blockIdx.x;
    int rb = bid >> 6;        // batch chunk 0..3
    int j  = bid & 63;        // gate-col chunk
    int row0 = rb << 6;

    // load W_hh slice into LDS; zero our region of h buffer 0
    {
        const ushort* wsrc = wphh + (size_t)(j << 6) * HH;
        for (int s = 0; s < 32; ++s) {
            int cidx = (s << 8) + tid;
            int c = cidx >> 7;
            int kc = cidx & 127;
            uint4 v = *(const uint4*)(wsrc + (size_t)c * HH + (kc << 3));
            *(uint4*)&wl[(kc >> 2) * 2048 + c * 32 + ((kc & 3) << 3)] = v;
        }
        int r = tid >> 2, hc = (tid & 3) << 2;
        ushort4 z = {0, 0, 0, 0};
        *(ushort4*)(hbf + (size_t)(row0 + r) * HH + (j << 4) + hc) = z;
    }

    int w = tid >> 6, l = tid & 63;
    int wm = w >> 1, wn = w & 1;
    int l15 = l & 15, kg = l >> 4;
    int r0 = tid >> 2, kk0 = (tid & 3) << 3;
    int lo0 = r0 * 32 + kk0;
    int lo1 = (64 + r0) * 32 + kk0;

    // recurrence-phase addressing
    const ushort* hrow0 = hbf + (size_t)(row0 + (w << 4) + l15) * HH + (kg << 3);
    int drow = row0 + (w << 4) + ((l >> 4) << 2);
    int hcol = (j << 4) + l15;
    ushort* hout0 = hbf + (size_t)drow * HH + hcol;
    const ushort* pbase = pre + (size_t)drow * G4 + (j << 6) + l15;
    float creg[4] = {0.f, 0.f, 0.f, 0.f};

    gridbar(bar);  // h0 zeroed grid-wide

    int nseg = TT / SEG;
    for (int sg = 0; sg < nseg; ++sg) {
        int t0 = sg * SEG;
        // ===== phase A: pre[t0..t0+SEG) = x @ W_ih^T + bias (chunk GEMM) =====
        int ntiles = SEG << 6;  // (SEG*256/128)*(4096/128)
        for (int q = bid; q < ntiles; q += 256) {
            int tm = q >> 5, tn = q & 31;
            int t = t0 + (tm >> 1);
            int b0 = (tm & 1) << 7;
            int n0 = tn << 7;
            const float* xa0 = x + ((size_t)(b0 + r0) * TT + t) * II + kk0;
            const float* xa1 = x + ((size_t)(b0 + 64 + r0) * TT + t) * II + kk0;
            const ushort* gb0 = wpih + (size_t)(n0 + r0) * II + kk0;
            const ushort* gb1 = wpih + (size_t)(n0 + 64 + r0) * II + kk0;
            f32x4 acc[4][4];
#pragma unroll
            for (int mi = 0; mi < 4; ++mi)
#pragma unroll
                for (int ni = 0; ni < 4; ++ni) acc[mi][ni] = f32x4{0.f, 0.f, 0.f, 0.f};
            for (int ko = 0; ko < 16; ++ko) {
                int k = ko * 32;
                float4 a0 = *(const float4*)(xa0 + k);
                float4 a1 = *(const float4*)(xa0 + k + 4);
                float4 a2 = *(const float4*)(xa1 + k);
                float4 a3 = *(const float4*)(xa1 + k + 4);
                uint4 vb0 = *(const uint4*)(gb0 + k);
                uint4 vb1 = *(const uint4*)(gb1 + k);
                union U8 { ushort us[8]; uint4 v; } pa, pb;
                pa.us[0] = f2bf(a0.x); pa.us[1] = f2bf(a0.y); pa.us[2] = f2bf(a0.z); pa.us[3] = f2bf(a0.w);
                pa.us[4] = f2bf(a1.x); pa.us[5] = f2bf(a1.y); pa.us[6] = f2bf(a1.z); pa.us[7] = f2bf(a1.w);
                pb.us[0] = f2bf(a2.x); pb.us[1] = f2bf(a2.y); pb.us[2] = f2bf(a2.z); pb.us[3] = f2bf(a2.w);
                pb.us[4] = f2bf(a3.x); pb.us[5] = f2bf(a3.y); pb.us[6] = f2bf(a3.z); pb.us[7] = f2bf(a3.w);
                __syncthreads();  // previous iter's LDS reads done
                *(uint4*)&Al[lo0] = pa.v;
                *(uint4*)&Al[lo1] = pb.v;
                *(uint4*)&Bl[lo0] = vb0;
                *(uint4*)&Bl[lo1] = vb1;
                __syncthreads();
                const ushort* Ab = &Al[wm * 64 * 32];
                const ushort* Bb = &Bl[wn * 64 * 32];
                bf8 af[4], bv[4];
#pragma unroll
                for (int mi = 0; mi < 4; ++mi)
                    af[mi] = *(const bf8*)(Ab + (mi * 16 + l15) * 32 + kg * 8);
#pragma unroll
                for (int ni = 0; ni < 4; ++ni)
                    bv[ni] = *(const bf8*)(Bb + (ni * 16 + l15) * 32 + kg * 8);
#pragma unroll
                for (int mi = 0; mi < 4; ++mi)
#pragma unroll
                    for (int ni = 0; ni < 4; ++ni)
                        acc[mi][ni] = __builtin_amdgcn_mfma_f32_16x16x32_bf16(af[mi], bv[ni], acc[mi][ni], 0, 0, 0);
            }
#pragma unroll
            for (int ni = 0; ni < 4; ++ni) {
                int col = n0 + wn * 64 + ni * 16 + l15;
                float bias = bp[col];
#pragma unroll
                for (int mi = 0; mi < 4; ++mi) {
                    int mrow = tm * 128 + wm * 64 + mi * 16 + ((l >> 4) << 2);
#pragma unroll
                    for (int r = 0; r < 4; ++r)
                        pre[(size_t)(mrow + r) * G4 + col] = f2bf(acc[mi][ni][r] + bias);
                }
            }
        }
        gridbar(bar);  // chunk ready grid-wide

        // ===== phase B: SEG recurrent steps =====
        ushort pr[16];
#pragma unroll
        for (int ni = 0; ni < 4; ++ni)
#pragma unroll
            for (int r = 0; r < 4; ++r) pr[ni * 4 + r] = pbase[(size_t)r * G4 + ni * 16];

        for (int trel = 0; trel < SEG; ++trel) {
            int t = t0 + trel;
            f32x4 acc[4];
#pragma unroll
            for (int ni = 0; ni < 4; ++ni)
#pragma unroll
                for (int r = 0; r < 4; ++r) acc[ni][r] = bf2f(pr[ni * 4 + r]);
            if (trel < SEG - 1) {
                const ushort* pn = pbase + (size_t)(trel + 1) * ((size_t)BB * G4);
#pragma unroll
                for (int ni = 0; ni < 4; ++ni)
#pragma unroll
                    for (int r = 0; r < 4; ++r) pr[ni * 4 + r] = pn[(size_t)r * G4 + ni * 16];
            }
            const ushort* hr = hrow0 + (size_t)(t & 1) * HBUF;
#pragma unroll 8
            for (int ko = 0; ko < 32; ++ko) {
                bf8 a = *(const bf8*)(hr + (ko << 5));
                const ushort* wb = &wl[ko * 2048 + (kg << 3)];
#pragma unroll
                for (int ni = 0; ni < 4; ++ni) {
                    bf8 b = *(const bf8*)(wb + ((ni * 16 + l15) << 5));
                    acc[ni] = __builtin_amdgcn_mfma_f32_16x16x32_bf16(a, b, acc[ni], 0, 0, 0);
                }
            }
            ushort* ho = hout0 + (size_t)((t & 1) ^ 1) * HBUF;
            bool last = (t == TT - 1);
#pragma unroll
            for (int r = 0; r < 4; ++r) {
                float ig = sigf(acc[0][r]);
                float fg = sigf(acc[1][r]);
                float gg = tanhf_(acc[2][r]);
                float og = sigf(acc[3][r]);
                float c = fg * creg[r] + ig * gg;
                creg[r] = c;
                float h = og * tanhf_(c);
                ho[(size_t)r * HH] = f2bf(h);
                if (last) {
                    dout[OUT_H + (size_t)(drow + r) * HH + hcol] = h;
                    dout[OUT_C + (size_t)(drow + r) * HH + hcol] = c;
                }
            }
            gridbar(bar);
        }
    }
}

// ---- FC: out = h @ W_fc^T + b_fc (M=256 N=512 K=1024); final h is in hbf buffer 0 ----
__global__ __launch_bounds__(256) void k_fc(const ushort* __restrict__ hbf,
                                            const ushort* __restrict__ wfc,
                                            const float* __restrict__ bfc,
                                            float* __restrict__ out) {
    int tid = threadIdx.x;
    int b0 = (blockIdx.x >> 3) << 6;
    int n0 = (blockIdx.x & 7) << 6;
    int w = tid >> 6, l = tid & 63;
    int l15 = l & 15, kg = l >> 4;
    const ushort* ha = hbf + (size_t)(b0 + (w << 4) + l15) * HH + (kg << 3);
    f32x4 acc[4];
#pragma unroll
    for (int ni = 0; ni < 4; ++ni) acc[ni] = f32x4{0.f, 0.f, 0.f, 0.f};
    for (int ko = 0; ko < 32; ++ko) {
        bf8 a = *(const bf8*)(ha + (ko << 5));
#pragma unroll
        for (int ni = 0; ni < 4; ++ni) {
            bf8 b = *(const bf8*)(wfc + (size_t)(n0 + ni * 16 + l15) * HH + (ko << 5) + (kg << 3));
            acc[ni] = __builtin_amdgcn_mfma_f32_16x16x32_bf16(a, b, acc[ni], 0, 0, 0);
        }
    }
    int drow = b0 + (w << 4) + ((l >> 4) << 2);
#pragma unroll
    for (int ni = 0; ni < 4; ++ni) {
        int col = n0 + ni * 16 + l15;
        float bias = bfc[col];
#pragma unroll
        for (int r = 0; r < 4; ++r)
            out[(size_t)(drow + r) * OO + col] = acc[ni][r] + bias;
    }
}

extern "C" void kernel_launch(void* const* d_in, const int* in_sizes, int n_in,
                              void* d_out, int out_size, void* d_ws, size_t ws_size,
                              hipStream_t stream) {
    const float* x   = (const float*)d_in[0];
    const float* Wih = (const float*)d_in[1];
    const float* Whh = (const float*)d_in[2];
    const float* bih = (const float*)d_in[3];
    const float* bhh = (const float*)d_in[4];
    const float* Wfc = (const float*)d_in[5];
    const float* bfc = (const float*)d_in[6];
    float* out = (float*)d_out;

    char* ws = (char*)d_ws;
    size_t off = 0;
    ushort* wpih = (ushort*)(ws + off); off += (size_t)G4 * II * 2;       // 4.2 MB
    ushort* wphh = (ushort*)(ws + off); off += (size_t)G4 * HH * 2;       // 8.4 MB
    ushort* wfcb = (ushort*)(ws + off); off += (size_t)OO * HH * 2;       // 1.0 MB
    float*  bp   = (float*)(ws + off);  off += (size_t)G4 * 4;            // 16 KB
    ushort* hbf  = (ushort*)(ws + off); off += (size_t)2 * BB * HH * 2;   // 1.0 MB
    int*    bar  = (int*)(ws + off);    off += 256;
    size_t fixed = off;
    int SEG = 16;
    while (SEG > 1 && fixed + (size_t)SEG * BB * G4 * 2 > ws_size) SEG >>= 1;
    ushort* pre = (ushort*)(ws + off);  // SEG*256*4096*2 bytes (<= 33.6 MB)

    k_init<<<1, 64, 0, stream>>>(bar);
    k_cast<<<256, 256, 0, stream>>>(Wfc, wfcb, OO * HH / 4);
    k_prep_w<<<G4, 256, 0, stream>>>(Wih, wpih, bih, bhh, bp, II);
    k_prep_w<<<G4, 256, 0, stream>>>(Whh, wphh, nullptr, nullptr, nullptr, HH);
    k_main<<<256, 256, 0, stream>>>(x, wpih, bp, pre, wphh, hbf, out, bar, SEG);
    k_fc<<<32, 256, 0, stream>>>(hbf, wfcb, bfc, out);
}

// Round 3
// 7314.462 us; speedup vs baseline: 1.0764x; 1.0764x over previous
//
#include <hip/hip_runtime.h>

typedef short bf8 __attribute__((ext_vector_type(8)));
typedef float f32x4 __attribute__((ext_vector_type(4)));

static constexpr int BB = 256;   // batch
static constexpr int TT = 128;   // time
static constexpr int II = 512;   // input features
static constexpr int HH = 1024;  // hidden
static constexpr int OO = 512;   // fc out features
static constexpr int G4 = 4096;  // 4*H

static constexpr size_t OUT_H = (size_t)BB * OO;          // h (f32) starts here in d_out
static constexpr size_t OUT_C = OUT_H + (size_t)BB * HH;  // c (f32) starts here
static constexpr size_t HBUF  = (size_t)BB * HH;          // ping-pong h buffer stride (elems)

__device__ __forceinline__ float bf2f(ushort u) {
    unsigned v = ((unsigned)u) << 16;
    return __builtin_bit_cast(float, v);
}
__device__ __forceinline__ ushort f2bf(float f) {
    unsigned x = __builtin_bit_cast(unsigned, f);
    x = x + 0x7FFFu + ((x >> 16) & 1u);   // round-to-nearest-even
    return (ushort)(x >> 16);
}
__device__ __forceinline__ float sigf(float x) { return 1.0f / (1.0f + __expf(-x)); }
__device__ __forceinline__ float tanhf_(float x) { return 2.0f * sigf(2.0f * x) - 1.0f; }

// ---- group barrier: 64 blocks, store+poll (no RMW contention) ----
// slots: one 128B-padded int per block in the group. gen is monotonic.
__device__ __forceinline__ void groupbar(int* slots, int bg, int gen) {
    __syncthreads();
    __threadfence();  // release: drain our global stores
    int tid = threadIdx.x;
    if (tid == 0)
        __hip_atomic_store(slots + bg * 32, gen, __ATOMIC_RELEASE, __HIP_MEMORY_SCOPE_AGENT);
    if (tid < 64) {
        while (__hip_atomic_load(slots + tid * 32, __ATOMIC_ACQUIRE, __HIP_MEMORY_SCOPE_AGENT) < gen)
            __builtin_amdgcn_s_sleep(4);
    }
    __threadfence();  // acquire: invalidate L1 so fresh h is seen
    __syncthreads();
}

__global__ void k_init(int* slots) {
    int i = blockIdx.x * 256 + threadIdx.x;
    if (i < 4 * 64 * 32) slots[i] = 0;
}

// ---- f32 -> bf16 flat cast (W_fc) ----
__global__ void k_cast(const float* __restrict__ src, ushort* __restrict__ dst, int n4) {
    int i = blockIdx.x * blockDim.x + threadIdx.x;
    int stride = gridDim.x * blockDim.x;
    for (; i < n4; i += stride) {
        float4 v = ((const float4*)src)[i];
        ushort4 o;
        o.x = f2bf(v.x); o.y = f2bf(v.y); o.z = f2bf(v.z); o.w = f2bf(v.w);
        ((ushort4*)dst)[i] = o;
    }
}

// ---- permute gate rows + cast W, fold biases ----
// permuted index p = j*64 + gate*16 + hc  ->  original row = gate*1024 + j*16 + hc
__global__ void k_prep_w(const float* __restrict__ w, ushort* __restrict__ wp,
                         const float* __restrict__ bi, const float* __restrict__ bh,
                         float* __restrict__ bp, int Kdim) {
    int p = blockIdx.x;
    int orig = ((p >> 4) & 3) * HH + ((p >> 6) << 4) + (p & 15);
    const float* src = w + (size_t)orig * Kdim;
    ushort* dst = wp + (size_t)p * Kdim;
    for (int k = threadIdx.x; k < Kdim; k += 256) dst[k] = f2bf(src[k]);
    if (threadIdx.x == 0 && bp) bp[p] = bi[orig] + bh[orig];
}

// ---- persistent kernel: 4 independent groups of 64 blocks (one batch-row chunk each) ----
// block = (g: 64 batch rows) x (j: 64 permuted gate cols = 16 hcols).
// W_hh slice resident in LDS (128 KiB, XOR-swizzled); GEMM staging 12 KiB.
__global__ __launch_bounds__(256) void k_main(
    const float* __restrict__ x, const ushort* __restrict__ wpih,
    const float* __restrict__ bp, ushort* __restrict__ pre,
    const ushort* __restrict__ wphh, ushort* __restrict__ hbf,
    float* __restrict__ dout, int* slots_all, int SEG) {
    __shared__ ushort wl[32 * 2048];  // 128 KiB: byte = ko*4096 + ((c*64 + kq*16) ^ ((c&7)<<4))
    __shared__ ushort Al[64 * 32];    // 4 KiB   (A: 64 rows x 32 k, swizzled)
    __shared__ ushort Bl[128 * 32];   // 8 KiB   (B: 128 rows x 32 k, swizzled)

    int tid = threadIdx.x;
    int bid = blockIdx.x;
    int g  = bid >> 6;        // batch-row group 0..3
    int bg = bid & 63;        // block-in-group == gate-col chunk j
    int j  = bg;
    int row0 = g << 6;
    int* slots = slots_all + g * 64 * 32;
    int gen = 0;

    // load W_hh slice into LDS (swizzled); zero our region of h buffer 0
    {
        const ushort* wsrc = wphh + (size_t)(j << 6) * HH;
        for (int s = 0; s < 32; ++s) {
            int cidx = (s << 8) + tid;   // 0..8191 16B-chunks
            int c = cidx >> 7;           // 0..63 gate col
            int kc = cidx & 127;         // 16B unit along K
            uint4 v = *(const uint4*)(wsrc + (size_t)c * HH + (kc << 3));
            int byte = ((kc >> 2) << 12) + ((((c << 6) + ((kc & 3) << 4))) ^ ((c & 7) << 4));
            *(uint4*)((char*)wl + byte) = v;
        }
        int r = tid >> 2, hc = (tid & 3) << 2;
        ushort4 z = {0, 0, 0, 0};
        *(ushort4*)(hbf + (size_t)(row0 + r) * HH + (j << 4) + hc) = z;
    }

    int w = tid >> 6, l = tid & 63;
    int wm = w >> 1, wn = w & 1;     // phase A: 2x2 waves over 64x128 tile
    int l15 = l & 15, kg = l >> 4;
    int swz = (l15 & 7) << 4;
    int wbase = ((l15 << 6) + (kg << 4)) ^ swz;   // per-lane swizzled frag byte base

    // phase A staging addresses
    int r0 = tid >> 2, kk = tid & 3;
    int sbyteA = ((r0 << 6) + (kk << 4)) ^ ((r0 & 7) << 4);
    int sbyteB1 = sbyteA + 4096;      // row r0+64 of B

    // phase B addressing
    const ushort* hrow0 = hbf + (size_t)(row0 + (w << 4) + l15) * HH + (kg << 3);
    int drow = row0 + (w << 4) + (kg << 2);
    int hcol = (j << 4) + l15;
    ushort* hout0 = hbf + (size_t)drow * HH + hcol;
    const ushort* pbase = pre + (size_t)drow * G4 + (j << 6) + l15;
    float creg[4] = {0.f, 0.f, 0.f, 0.f};

    int nseg = TT / SEG;
    for (int sg = 0; sg < nseg; ++sg) {
        int t0 = sg * SEG;
        // ===== phase A: pre[t0..t0+SEG) for our 64 batch rows (tiles 64x128, K=512) =====
        int ntiles = SEG << 5;
        for (int q = bg; q < ntiles; q += 64) {
            int trel = q >> 5;
            int t = t0 + trel;
            int n0 = (q & 31) << 7;
            const float* xa = x + ((size_t)(row0 + r0) * TT + t) * II + (kk << 3);
            const ushort* gb0 = wpih + (size_t)(n0 + r0) * II + (kk << 3);
            const ushort* gb1 = gb0 + (size_t)64 * II;
            f32x4 acc[2][4];
#pragma unroll
            for (int mi = 0; mi < 2; ++mi)
#pragma unroll
                for (int ni = 0; ni < 4; ++ni) acc[mi][ni] = f32x4{0.f, 0.f, 0.f, 0.f};
            float4 a0 = *(const float4*)xa;
            float4 a1 = *(const float4*)(xa + 4);
            uint4 b0v = *(const uint4*)gb0;
            uint4 b1v = *(const uint4*)gb1;
            for (int ko = 0; ko < 16; ++ko) {
                union { ushort us[8]; uint4 v; } pa;
                pa.us[0] = f2bf(a0.x); pa.us[1] = f2bf(a0.y); pa.us[2] = f2bf(a0.z); pa.us[3] = f2bf(a0.w);
                pa.us[4] = f2bf(a1.x); pa.us[5] = f2bf(a1.y); pa.us[6] = f2bf(a1.z); pa.us[7] = f2bf(a1.w);
                __syncthreads();  // prior LDS reads done
                *(uint4*)((char*)Al + sbyteA) = pa.v;
                *(uint4*)((char*)Bl + sbyteA) = b0v;
                *(uint4*)((char*)Bl + sbyteB1) = b1v;
                __syncthreads();
                if (ko < 15) {  // prefetch next K-slice; latency hides under ds_read+MFMA
                    int k = (ko + 1) << 5;
                    a0 = *(const float4*)(xa + k);
                    a1 = *(const float4*)(xa + k + 4);
                    b0v = *(const uint4*)(gb0 + k);
                    b1v = *(const uint4*)(gb1 + k);
                }
                bf8 af[2], bv[4];
#pragma unroll
                for (int mi = 0; mi < 2; ++mi)
                    af[mi] = *(const bf8*)((char*)Al + wm * 2048 + mi * 1024 + wbase);
#pragma unroll
                for (int ni = 0; ni < 4; ++ni)
                    bv[ni] = *(const bf8*)((char*)Bl + wn * 4096 + ni * 1024 + wbase);
#pragma unroll
                for (int mi = 0; mi < 2; ++mi)
#pragma unroll
                    for (int ni = 0; ni < 4; ++ni)
                        acc[mi][ni] = __builtin_amdgcn_mfma_f32_16x16x32_bf16(af[mi], bv[ni], acc[mi][ni], 0, 0, 0);
            }
#pragma unroll
            for (int ni = 0; ni < 4; ++ni) {
                int col = n0 + wn * 64 + ni * 16 + l15;
                float bias = bp[col];
#pragma unroll
                for (int mi = 0; mi < 2; ++mi) {
                    int arow = row0 + wm * 32 + mi * 16 + (kg << 2);
#pragma unroll
                    for (int r = 0; r < 4; ++r)
                        pre[((size_t)trel * BB + arow + r) * G4 + col] = f2bf(acc[mi][ni][r] + bias);
                }
            }
        }
        gen++; groupbar(slots, bg, gen);  // pre chunk + (sg==0) h0 zero visible group-wide

        // ===== phase B: SEG recurrent steps =====
        ushort pr[16];
#pragma unroll
        for (int ni = 0; ni < 4; ++ni)
#pragma unroll
            for (int r = 0; r < 4; ++r) pr[ni * 4 + r] = pbase[(size_t)r * G4 + ni * 16];

        for (int trel = 0; trel < SEG; ++trel) {
            int t = t0 + trel;
            f32x4 acc[4];
#pragma unroll
            for (int ni = 0; ni < 4; ++ni)
#pragma unroll
                for (int r = 0; r < 4; ++r) acc[ni][r] = bf2f(pr[ni * 4 + r]);
            if (trel < SEG - 1) {
                const ushort* pn = pbase + (size_t)(trel + 1) * ((size_t)BB * G4);
#pragma unroll
                for (int ni = 0; ni < 4; ++ni)
#pragma unroll
                    for (int r = 0; r < 4; ++r) pr[ni * 4 + r] = pn[(size_t)r * G4 + ni * 16];
            }
            const ushort* hr = hrow0 + (size_t)(t & 1) * HBUF;
#pragma unroll 8
            for (int ko = 0; ko < 32; ++ko) {
                bf8 a = *(const bf8*)(hr + (ko << 5));
#pragma unroll
                for (int ni = 0; ni < 4; ++ni) {
                    bf8 b = *(const bf8*)((char*)wl + ko * 4096 + ni * 1024 + wbase);
                    acc[ni] = __builtin_amdgcn_mfma_f32_16x16x32_bf16(a, b, acc[ni], 0, 0, 0);
                }
            }
            ushort* ho = hout0 + (size_t)((t & 1) ^ 1) * HBUF;
            bool last = (t == TT - 1);
#pragma unroll
            for (int r = 0; r < 4; ++r) {
                float ig = sigf(acc[0][r]);
                float fg = sigf(acc[1][r]);
                float gg = tanhf_(acc[2][r]);
                float og = sigf(acc[3][r]);
                float c = fg * creg[r] + ig * gg;
                creg[r] = c;
                float h = og * tanhf_(c);
                ho[(size_t)r * HH] = f2bf(h);
                if (last) {
                    dout[OUT_H + (size_t)(drow + r) * HH + hcol] = h;
                    dout[OUT_C + (size_t)(drow + r) * HH + hcol] = c;
                }
            }
            gen++; groupbar(slots, bg, gen);
        }
    }
}

// ---- FC: out = h @ W_fc^T + b_fc (M=256 N=512 K=1024); final h is in hbf buffer 0 ----
__global__ __launch_bounds__(256) void k_fc(const ushort* __restrict__ hbf,
                                            const ushort* __restrict__ wfc,
                                            const float* __restrict__ bfc,
                                            float* __restrict__ out) {
    int tid = threadIdx.x;
    int b0 = (blockIdx.x >> 3) << 6;
    int n0 = (blockIdx.x & 7) << 6;
    int w = tid >> 6, l = tid & 63;
    int l15 = l & 15, kg = l >> 4;
    const ushort* ha = hbf + (size_t)(b0 + (w << 4) + l15) * HH + (kg << 3);
    f32x4 acc[4];
#pragma unroll
    for (int ni = 0; ni < 4; ++ni) acc[ni] = f32x4{0.f, 0.f, 0.f, 0.f};
    for (int ko = 0; ko < 32; ++ko) {
        bf8 a = *(const bf8*)(ha + (ko << 5));
#pragma unroll
        for (int ni = 0; ni < 4; ++ni) {
            bf8 b = *(const bf8*)(wfc + (size_t)(n0 + ni * 16 + l15) * HH + (ko << 5) + (kg << 3));
            acc[ni] = __builtin_amdgcn_mfma_f32_16x16x32_bf16(a, b, acc[ni], 0, 0, 0);
        }
    }
    int drow = b0 + (w << 4) + (kg << 2);
#pragma unroll
    for (int ni = 0; ni < 4; ++ni) {
        int col = n0 + ni * 16 + l15;
        float bias = bfc[col];
#pragma unroll
        for (int r = 0; r < 4; ++r)
            out[(size_t)(drow + r) * OO + col] = acc[ni][r] + bias;
    }
}

extern "C" void kernel_launch(void* const* d_in, const int* in_sizes, int n_in,
                              void* d_out, int out_size, void* d_ws, size_t ws_size,
                              hipStream_t stream) {
    const float* x   = (const float*)d_in[0];
    const float* Wih = (const float*)d_in[1];
    const float* Whh = (const float*)d_in[2];
    const float* bih = (const float*)d_in[3];
    const float* bhh = (const float*)d_in[4];
    const float* Wfc = (const float*)d_in[5];
    const float* bfc = (const float*)d_in[6];
    float* out = (float*)d_out;

    char* ws = (char*)d_ws;
    size_t off = 0;
    ushort* wpih = (ushort*)(ws + off); off += (size_t)G4 * II * 2;       // 4.2 MB
    ushort* wphh = (ushort*)(ws + off); off += (size_t)G4 * HH * 2;       // 8.4 MB
    ushort* wfcb = (ushort*)(ws + off); off += (size_t)OO * HH * 2;       // 1.0 MB
    float*  bp   = (float*)(ws + off);  off += (size_t)G4 * 4;            // 16 KB
    ushort* hbf  = (ushort*)(ws + off); off += (size_t)2 * BB * HH * 2;   // 1.0 MB
    int*    slots= (int*)(ws + off);    off += (size_t)4 * 64 * 32 * 4;   // 32 KB
    size_t fixed = off;
    int SEG = 16;
    while (SEG > 1 && fixed + (size_t)SEG * BB * G4 * 2 > ws_size) SEG >>= 1;
    ushort* pre = (ushort*)(ws + off);  // SEG*256*4096*2 bytes (<= 33.6 MB)

    k_init<<<32, 256, 0, stream>>>(slots);
    k_cast<<<256, 256, 0, stream>>>(Wfc, wfcb, OO * HH / 4);
    k_prep_w<<<G4, 256, 0, stream>>>(Wih, wpih, bih, bhh, bp, II);
    k_prep_w<<<G4, 256, 0, stream>>>(Whh, wphh, nullptr, nullptr, nullptr, HH);
    k_main<<<256, 256, 0, stream>>>(x, wpih, bp, pre, wphh, hbf, out, slots, SEG);
    k_fc<<<32, 256, 0, stream>>>(hbf, wfcb, bfc, out);
}

// Round 4
// 1648.512 us; speedup vs baseline: 4.7759x; 4.4370x over previous
//
#include <hip/hip_runtime.h>

typedef short bf8 __attribute__((ext_vector_type(8)));
typedef float f32x4 __attribute__((ext_vector_type(4)));

static constexpr int BB = 256;   // batch
static constexpr int TT = 128;   // time
static constexpr int II = 512;   // input features
static constexpr int HH = 1024;  // hidden
static constexpr int OO = 512;   // fc out features
static constexpr int G4 = 4096;  // 4*H

static constexpr size_t OUT_H = (size_t)BB * OO;          // h (f32) starts here in d_out
static constexpr size_t OUT_C = OUT_H + (size_t)BB * HH;  // c (f32) starts here
static constexpr size_t HBUF  = (size_t)BB * HH;          // ping-pong h buffer stride (elems)

__device__ __forceinline__ float bf2f(ushort u) {
    unsigned v = ((unsigned)u) << 16;
    return __builtin_bit_cast(float, v);
}
__device__ __forceinline__ ushort f2bf(float f) {
    unsigned x = __builtin_bit_cast(unsigned, f);
    x = x + 0x7FFFu + ((x >> 16) & 1u);   // round-to-nearest-even
    return (ushort)(x >> 16);
}
__device__ __forceinline__ float sigf(float x) { return 1.0f / (1.0f + __expf(-x)); }
__device__ __forceinline__ float tanhf_(float x) { return 2.0f * sigf(2.0f * x) - 1.0f; }

// ---- coherence-point (bypass) memory ops: no L2 dirty state, no fences needed ----
__device__ __forceinline__ void st_wt_short(const ushort* p, uint v) {
    asm volatile("global_store_short %0, %1, off sc0 sc1" :: "v"(p), "v"(v) : "memory");
}
__device__ __forceinline__ void st_wt_b64(const ushort* p, uint2 v) {
    asm volatile("global_store_dwordx2 %0, %1, off sc0 sc1" :: "v"(p), "v"(v) : "memory");
}
__device__ __forceinline__ void ld_bp_ushort_issue(uint& dst, const ushort* p) {
    asm volatile("global_load_ushort %0, %1, off sc0 sc1" : "=v"(dst) : "v"(p) : "memory");
}
__device__ __forceinline__ void ld_bp_b128_issue(uint4& dst, const ushort* p) {
    asm volatile("global_load_dwordx4 %0, %1, off sc0 sc1" : "=v"(dst) : "v"(p) : "memory");
}
__device__ __forceinline__ void wait_vm0() {
    asm volatile("s_waitcnt vmcnt(0)" ::: "memory");
    __builtin_amdgcn_sched_barrier(0);
}

// ---- light group barrier: 64 blocks, raw coherence-point flags, ZERO cache fences ----
__device__ __forceinline__ void lightbar(int* slots, int bg, int gen) {
    asm volatile("s_waitcnt vmcnt(0) lgkmcnt(0)" ::: "memory");  // drain own WT stores
    __builtin_amdgcn_sched_barrier(0);
    __syncthreads();
    int tid = threadIdx.x;
    if (tid == 0) {
        asm volatile("global_store_dword %0, %1, off sc0 sc1" :: "v"(slots + bg * 32), "v"(gen) : "memory");
    }
    if (tid < 64) {
        const int* sp = slots + tid * 32;
        int v;
        do {
            asm volatile("global_load_dword %0, %1, off sc0 sc1\n\ts_waitcnt vmcnt(0)"
                         : "=v"(v) : "v"(sp) : "memory");
            if (v >= gen) break;
            __builtin_amdgcn_s_sleep(1);
        } while (true);
    }
    __syncthreads();
}

__global__ void k_init(int* slots) {
    int i = blockIdx.x * 256 + threadIdx.x;
    if (i < 4 * 64 * 32) slots[i] = 0;
}

// ---- f32 -> bf16 flat cast (W_fc) ----
__global__ void k_cast(const float* __restrict__ src, ushort* __restrict__ dst, int n4) {
    int i = blockIdx.x * blockDim.x + threadIdx.x;
    int stride = gridDim.x * blockDim.x;
    for (; i < n4; i += stride) {
        float4 v = ((const float4*)src)[i];
        ushort4 o;
        o.x = f2bf(v.x); o.y = f2bf(v.y); o.z = f2bf(v.z); o.w = f2bf(v.w);
        ((ushort4*)dst)[i] = o;
    }
}

// ---- permute gate rows + cast W, fold biases ----
// permuted index p = j*64 + gate*16 + hc  ->  original row = gate*1024 + j*16 + hc
__global__ void k_prep_w(const float* __restrict__ w, ushort* __restrict__ wp,
                         const float* __restrict__ bi, const float* __restrict__ bh,
                         float* __restrict__ bp, int Kdim) {
    int p = blockIdx.x;
    int orig = ((p >> 4) & 3) * HH + ((p >> 6) << 4) + (p & 15);
    const float* src = w + (size_t)orig * Kdim;
    ushort* dst = wp + (size_t)p * Kdim;
    for (int k = threadIdx.x; k < Kdim; k += 256) dst[k] = f2bf(src[k]);
    if (threadIdx.x == 0 && bp) bp[p] = bi[orig] + bh[orig];
}

// ---- persistent kernel: 4 independent groups of 64 blocks (one batch-row chunk each) ----
// block = (g: 64 batch rows) x (j: 64 permuted gate cols = 16 hcols).
// W_hh slice resident in LDS (128 KiB); GEMM staging 12 KiB. 1 block/CU.
// Cross-block data (h, pre) goes write-through to the memory-side coherence point and is
// read with L2-bypass loads -> no stale-copy hazard -> no buffer_wbl2/buffer_inv ever.
__global__ __launch_bounds__(256) void k_main(
    const float* __restrict__ x, const ushort* __restrict__ wpih,
    const float* __restrict__ bp, ushort* __restrict__ pre,
    const ushort* __restrict__ wphh, ushort* __restrict__ hbf,
    float* __restrict__ dout, int* slots_all, int SEG) {
    __shared__ ushort wl[32 * 2048];  // 128 KiB
    __shared__ ushort Al[64 * 32];    // 4 KiB
    __shared__ ushort Bl[128 * 32];   // 8 KiB

    int tid = threadIdx.x;
    int bid = blockIdx.x;
    int g  = bid >> 6;        // batch-row group 0..3
    int bg = bid & 63;        // block-in-group == gate-col chunk j
    int j  = bg;
    int row0 = g << 6;
    int* slots = slots_all + g * 64 * 32;
    int gen = 0;

    // load W_hh slice into LDS (swizzled); zero our region of h buffer 0 (write-through)
    {
        const ushort* wsrc = wphh + (size_t)(j << 6) * HH;
        for (int s = 0; s < 32; ++s) {
            int cidx = (s << 8) + tid;
            int c = cidx >> 7;
            int kc = cidx & 127;
            uint4 v = *(const uint4*)(wsrc + (size_t)c * HH + (kc << 3));
            int byte = ((kc >> 2) << 12) + ((((c << 6) + ((kc & 3) << 4))) ^ ((c & 7) << 4));
            *(uint4*)((char*)wl + byte) = v;
        }
        int r = tid >> 2, hc = (tid & 3) << 2;
        uint2 z; z.x = 0; z.y = 0;
        st_wt_b64(hbf + (size_t)(row0 + r) * HH + (j << 4) + hc, z);
    }

    int w = tid >> 6, l = tid & 63;
    int wm = w >> 1, wn = w & 1;     // phase A: 2x2 waves over 64x128 tile
    int l15 = l & 15, kg = l >> 4;
    int swz = (l15 & 7) << 4;
    int wbase = ((l15 << 6) + (kg << 4)) ^ swz;   // per-lane swizzled frag byte base

    // phase A staging addresses
    int r0 = tid >> 2, kk = tid & 3;
    int sbyteA = ((r0 << 6) + (kk << 4)) ^ ((r0 & 7) << 4);
    int sbyteB1 = sbyteA + 4096;      // row r0+64 of B

    // phase B addressing
    const ushort* hrow0 = hbf + (size_t)(row0 + (w << 4) + l15) * HH + (kg << 3);
    int drow = row0 + (w << 4) + (kg << 2);
    int hcol = (j << 4) + l15;
    ushort* hout0 = hbf + (size_t)drow * HH + hcol;
    const ushort* pbase = pre + (size_t)drow * G4 + (j << 6) + l15;
    float creg[4] = {0.f, 0.f, 0.f, 0.f};

    int nseg = TT / SEG;
    for (int sg = 0; sg < nseg; ++sg) {
        int t0 = sg * SEG;
        // ===== phase A: pre[t0..t0+SEG) for our 64 batch rows (tiles 64x128, K=512) =====
        int ntiles = SEG << 5;
        for (int q = bg; q < ntiles; q += 64) {
            int trel = q >> 5;
            int t = t0 + trel;
            int n0 = (q & 31) << 7;
            const float* xa = x + ((size_t)(row0 + r0) * TT + t) * II + (kk << 3);
            const ushort* gb0 = wpih + (size_t)(n0 + r0) * II + (kk << 3);
            const ushort* gb1 = gb0 + (size_t)64 * II;
            f32x4 acc[2][4];
#pragma unroll
            for (int mi = 0; mi < 2; ++mi)
#pragma unroll
                for (int ni = 0; ni < 4; ++ni) acc[mi][ni] = f32x4{0.f, 0.f, 0.f, 0.f};
            float4 a0 = *(const float4*)xa;
            float4 a1 = *(const float4*)(xa + 4);
            uint4 b0v = *(const uint4*)gb0;
            uint4 b1v = *(const uint4*)gb1;
            for (int ko = 0; ko < 16; ++ko) {
                union { ushort us[8]; uint4 v; } pa;
                pa.us[0] = f2bf(a0.x); pa.us[1] = f2bf(a0.y); pa.us[2] = f2bf(a0.z); pa.us[3] = f2bf(a0.w);
                pa.us[4] = f2bf(a1.x); pa.us[5] = f2bf(a1.y); pa.us[6] = f2bf(a1.z); pa.us[7] = f2bf(a1.w);
                __syncthreads();  // prior LDS reads done
                *(uint4*)((char*)Al + sbyteA) = pa.v;
                *(uint4*)((char*)Bl + sbyteA) = b0v;
                *(uint4*)((char*)Bl + sbyteB1) = b1v;
                __syncthreads();
                if (ko < 15) {  // prefetch next K-slice
                    int k = (ko + 1) << 5;
                    a0 = *(const float4*)(xa + k);
                    a1 = *(const float4*)(xa + k + 4);
                    b0v = *(const uint4*)(gb0 + k);
                    b1v = *(const uint4*)(gb1 + k);
                }
                bf8 af[2], bv[4];
#pragma unroll
                for (int mi = 0; mi < 2; ++mi)
                    af[mi] = *(const bf8*)((char*)Al + wm * 2048 + mi * 1024 + wbase);
#pragma unroll
                for (int ni = 0; ni < 4; ++ni)
                    bv[ni] = *(const bf8*)((char*)Bl + wn * 4096 + ni * 1024 + wbase);
#pragma unroll
                for (int mi = 0; mi < 2; ++mi)
#pragma unroll
                    for (int ni = 0; ni < 4; ++ni)
                        acc[mi][ni] = __builtin_amdgcn_mfma_f32_16x16x32_bf16(af[mi], bv[ni], acc[mi][ni], 0, 0, 0);
            }
            // epilogue: write-through pre stores (visible at coherence point before flag)
#pragma unroll
            for (int ni = 0; ni < 4; ++ni) {
                int col = n0 + wn * 64 + ni * 16 + l15;
                float bias = bp[col];
#pragma unroll
                for (int mi = 0; mi < 2; ++mi) {
                    int arow = row0 + wm * 32 + mi * 16 + (kg << 2);
#pragma unroll
                    for (int r = 0; r < 4; ++r) {
                        const ushort* pp = pre + ((size_t)trel * BB + arow + r) * G4 + col;
                        st_wt_short(pp, (uint)f2bf(acc[mi][ni][r] + bias));
                    }
                }
            }
        }
        gen++; lightbar(slots, bg, gen);  // pre chunk + (sg==0) h0 zero visible group-wide

        // ===== phase B: SEG recurrent steps =====
        uint prn[16];
#pragma unroll
        for (int ni = 0; ni < 4; ++ni)
#pragma unroll
            for (int r = 0; r < 4; ++r)
                ld_bp_ushort_issue(prn[ni * 4 + r], pbase + (size_t)r * G4 + ni * 16);

        for (int trel = 0; trel < SEG; ++trel) {
            int t = t0 + trel;
            wait_vm0();  // prn ready (drained here or at previous barrier)
            f32x4 acc[4];
#pragma unroll
            for (int ni = 0; ni < 4; ++ni)
#pragma unroll
                for (int r = 0; r < 4; ++r) acc[ni][r] = bf2f((ushort)prn[ni * 4 + r]);

            const ushort* hr = hrow0 + (size_t)(t & 1) * HBUF;
#pragma unroll
            for (int c = 0; c < 4; ++c) {
                uint4 hv[8];
#pragma unroll
                for (int u = 0; u < 8; ++u)
                    ld_bp_b128_issue(hv[u], hr + ((c * 8 + u) << 5));
                wait_vm0();
#pragma unroll
                for (int u = 0; u < 8; ++u) {
                    int ko = c * 8 + u;
                    bf8 a = __builtin_bit_cast(bf8, hv[u]);
#pragma unroll
                    for (int ni = 0; ni < 4; ++ni) {
                        bf8 b = *(const bf8*)((char*)wl + ko * 4096 + ni * 1024 + wbase);
                        acc[ni] = __builtin_amdgcn_mfma_f32_16x16x32_bf16(a, b, acc[ni], 0, 0, 0);
                    }
                }
            }

            if (trel < SEG - 1) {  // prefetch next step's pre slice; drains by next wait_vm0
                const ushort* pn = pbase + (size_t)(trel + 1) * ((size_t)BB * G4);
#pragma unroll
                for (int ni = 0; ni < 4; ++ni)
#pragma unroll
                    for (int r = 0; r < 4; ++r)
                        ld_bp_ushort_issue(prn[ni * 4 + r], pn + (size_t)r * G4 + ni * 16);
            }

            ushort* ho = hout0 + (size_t)((t & 1) ^ 1) * HBUF;
            bool last = (t == TT - 1);
#pragma unroll
            for (int r = 0; r < 4; ++r) {
                float ig = sigf(acc[0][r]);
                float fg = sigf(acc[1][r]);
                float gg = tanhf_(acc[2][r]);
                float og = sigf(acc[3][r]);
                float c = fg * creg[r] + ig * gg;
                creg[r] = c;
                float h = og * tanhf_(c);
                st_wt_short(ho + (size_t)r * HH, (uint)f2bf(h));
                if (last) {
                    dout[OUT_H + (size_t)(drow + r) * HH + hcol] = h;
                    dout[OUT_C + (size_t)(drow + r) * HH + hcol] = c;
                }
            }
            gen++; lightbar(slots, bg, gen);
        }
    }
}

// ---- FC: out = h @ W_fc^T + b_fc (M=256 N=512 K=1024); final h is in hbf buffer 0 ----
__global__ __launch_bounds__(256) void k_fc(const ushort* __restrict__ hbf,
                                            const ushort* __restrict__ wfc,
                                            const float* __restrict__ bfc,
                                            float* __restrict__ out) {
    int tid = threadIdx.x;
    int b0 = (blockIdx.x >> 3) << 6;
    int n0 = (blockIdx.x & 7) << 6;
    int w = tid >> 6, l = tid & 63;
    int l15 = l & 15, kg = l >> 4;
    const ushort* ha = hbf + (size_t)(b0 + (w << 4) + l15) * HH + (kg << 3);
    f32x4 acc[4];
#pragma unroll
    for (int ni = 0; ni < 4; ++ni) acc[ni] = f32x4{0.f, 0.f, 0.f, 0.f};
    for (int ko = 0; ko < 32; ++ko) {
        bf8 a = *(const bf8*)(ha + (ko << 5));
#pragma unroll
        for (int ni = 0; ni < 4; ++ni) {
            bf8 b = *(const bf8*)(wfc + (size_t)(n0 + ni * 16 + l15) * HH + (ko << 5) + (kg << 3));
            acc[ni] = __builtin_amdgcn_mfma_f32_16x16x32_bf16(a, b, acc[ni], 0, 0, 0);
        }
    }
    int drow = b0 + (w << 4) + (kg << 2);
#pragma unroll
    for (int ni = 0; ni < 4; ++ni) {
        int col = n0 + ni * 16 + l15;
        float bias = bfc[col];
#pragma unroll
        for (int r = 0; r < 4; ++r)
            out[(size_t)(drow + r) * OO + col] = acc[ni][r] + bias;
    }
}

extern "C" void kernel_launch(void* const* d_in, const int* in_sizes, int n_in,
                              void* d_out, int out_size, void* d_ws, size_t ws_size,
                              hipStream_t stream) {
    const float* x   = (const float*)d_in[0];
    const float* Wih = (const float*)d_in[1];
    const float* Whh = (const float*)d_in[2];
    const float* bih = (const float*)d_in[3];
    const float* bhh = (const float*)d_in[4];
    const float* Wfc = (const float*)d_in[5];
    const float* bfc = (const float*)d_in[6];
    float* out = (float*)d_out;

    char* ws = (char*)d_ws;
    size_t off = 0;
    ushort* wpih = (ushort*)(ws + off); off += (size_t)G4 * II * 2;       // 4.2 MB
    ushort* wphh = (ushort*)(ws + off); off += (size_t)G4 * HH * 2;       // 8.4 MB
    ushort* wfcb = (ushort*)(ws + off); off += (size_t)OO * HH * 2;       // 1.0 MB
    float*  bp   = (float*)(ws + off);  off += (size_t)G4 * 4;            // 16 KB
    ushort* hbf  = (ushort*)(ws + off); off += (size_t)2 * BB * HH * 2;   // 1.0 MB
    int*    slots= (int*)(ws + off);    off += (size_t)4 * 64 * 32 * 4;   // 32 KB
    size_t fixed = off;
    int SEG = 16;
    while (SEG > 1 && fixed + (size_t)SEG * BB * G4 * 2 > ws_size) SEG >>= 1;
    ushort* pre = (ushort*)(ws + off);  // SEG*256*4096*2 bytes (<= 33.6 MB)

    k_init<<<32, 256, 0, stream>>>(slots);
    k_cast<<<256, 256, 0, stream>>>(Wfc, wfcb, OO * HH / 4);
    k_prep_w<<<G4, 256, 0, stream>>>(Wih, wpih, bih, bhh, bp, II);
    k_prep_w<<<G4, 256, 0, stream>>>(Whh, wphh, nullptr, nullptr, nullptr, HH);
    k_main<<<256, 256, 0, stream>>>(x, wpih, bp, pre, wphh, hbf, out, slots, SEG);
    k_fc<<<32, 256, 0, stream>>>(hbf, wfcb, bfc, out);
}